// Round 10
// baseline (25.763 us; speedup 1.0000x reference)
//
#include <hip/hip_runtime.h>
#include <hip/hip_bf16.h>

#define NB 2048

typedef __attribute__((ext_vector_type(8))) short bf16x8;
typedef __attribute__((ext_vector_type(4))) float f32x4;

__device__ __forceinline__ float qget(const float4& q, int c) {
    return c == 0 ? q.x : c == 1 ? q.y : c == 2 ? q.z : q.w;
}

// ONE WAVE PER BATCH. block=64, grid=2048, zero __syncthreads.
// Lane l owns 4 gamma rows (k_j, i): i = l&15, k_j = (l>>4) + 4j, j=0..3.
// scalar[b] = <Aprev-Acur,Minv> - sum_i dT[i]*R[i] + sum_m T[m]*Q[m] - <term4,Minv>
// term4 = 16x16x256 bf16 MFMA (one wave, 8 K-steps, acc accumulates).
//   A[i][l]=XA[i][l]; B[l][j]=XA[l>>4][(l&15)*16+j] (u16 gather, slot-consistent l).
// GJ: whole-wave shuffle Gauss-Jordan (SPD metric, eig>=1, no pivoting).
__global__ __launch_bounds__(64, 4)
void curvature_kernel(const float* __restrict__ metric,
                      const float* __restrict__ gamma,
                      float* __restrict__ out)
{
    const int bid = blockIdx.x;
    const int b = ((bid & 7) << 8) | (bid >> 3);   // XCD swizzle: b, b-1 share an L2
    const int l = threadIdx.x;                      // lane 0..63
    const int iu = l & 15;                          // my row-within-plane (all 4 rows)
    const int kb = l >> 4;                          // plane base: k_j = kb + 4j

    __shared__ alignas(16) unsigned short XA[16][264];  // XA[i][m*16+c] = G[m,i,c]
    __shared__ alignas(16) float MINV[16][20];

    const float* Gc = gamma + ((size_t)b << 12);
    const float* Gp = gamma + ((size_t)((b + NB - 1) & (NB - 1)) << 12);
    const int rbase = (kb << 8) + (iu << 4);        // row (kb+4j, iu) at + j*1024

    // ---- issue loads: metric first (GJ dep), then cur, then prev half ----
    float4 mrow = ((const float4*)(metric + ((size_t)b << 8)))[l];
    float4 cq[4][4];
    #pragma unroll
    for (int j = 0; j < 4; ++j) {
        const float4* src = (const float4*)(Gc + rbase + (j << 10));
        cq[j][0] = src[0]; cq[j][1] = src[1]; cq[j][2] = src[2]; cq[j][3] = src[3];
    }
    float4 pq[2][4];
    #pragma unroll
    for (int j = 0; j < 2; ++j) {
        const float4* src = (const float4*)(Gp + rbase + (j << 10));
        pq[j][0] = src[0]; pq[j][1] = src[1]; pq[j][2] = src[2]; pq[j][3] = src[3];
    }

    // ---- stage XA (bf16 pack, contiguous b128 writes) + cur diag partial ----
    float tc = 0.f;
    #pragma unroll
    for (int j = 0; j < 4; ++j) {
        unsigned yp[8];
        #pragma unroll
        for (int q = 0; q < 8; ++q) {
            union { __hip_bfloat162 h; unsigned u; } cv;
            cv.h = __float22bfloat162_rn(
                make_float2(qget(cq[j][q >> 1], (q & 1) * 2),
                            qget(cq[j][q >> 1], (q & 1) * 2 + 1)));
            yp[q] = cv.u;
        }
        uint4* xd = (uint4*)&XA[iu][(kb + 4 * j) << 4];
        xd[0] = make_uint4(yp[0], yp[1], yp[2], yp[3]);
        xd[1] = make_uint4(yp[4], yp[5], yp[6], yp[7]);
        tc += qget(cq[j][j], kb);      // G[k_j, iu, k_j]: quad j, comp kb (static quad)
    }

    // ---- whole-wave shuffle Gauss-Jordan inverse of metric ----
    {
        const int gi = l >> 2, gq2 = l & 3;
        float a0 = mrow.x, a1 = mrow.y, a2 = mrow.z, a3 = mrow.w;
        #pragma unroll
        for (int k = 0; k < 16; ++k) {
            const int kq = k >> 2, kc = k & 3;
            float akc = (kc == 0) ? a0 : (kc == 1) ? a1 : (kc == 2) ? a2 : a3;
            float pv = __shfl(akc, (k << 2) | kq);
            float f  = __shfl(akc, (l & 60) | kq);
            float q0 = __shfl(a0, (k << 2) | gq2);
            float q1 = __shfl(a1, (k << 2) | gq2);
            float q2 = __shfl(a2, (k << 2) | gq2);
            float q3 = __shfl(a3, (k << 2) | gq2);
            float pinv = 1.0f / pv;
            bool piv = (gi == k);
            float r0 = q0*pinv, r1 = q1*pinv, r2 = q2*pinv, r3 = q3*pinv;
            a0 = piv ? r0 : fmaf(-f, r0, a0);
            a1 = piv ? r1 : fmaf(-f, r1, a1);
            a2 = piv ? r2 : fmaf(-f, r2, a2);
            a3 = piv ? r3 : fmaf(-f, r3, a3);
            if (gq2 == kq) {
                float colv = piv ? pinv : -f * pinv;
                if      (kc == 0) a0 = colv;
                else if (kc == 1) a1 = colv;
                else if (kc == 2) a2 = colv;
                else              a3 = colv;
            }
        }
        ((float4*)&MINV[gi][4 * gq2])[0] = make_float4(a0, a1, a2, a3);
    }
    // compiler fence: XA/MINV writes stay before the reads below (single-wave
    // DS ops execute in order; no s_barrier needed)
    asm volatile("" ::: "memory");

    // ---- mr = MINV[iu][:], R = row sum ----
    float mr[16];
    {
        const float4* mv = (const float4*)&MINV[iu][0];
        float4 m0 = mv[0], m1 = mv[1], m2 = mv[2], m3 = mv[3];
        mr[0]=m0.x; mr[1]=m0.y; mr[2]=m0.z; mr[3]=m0.w;
        mr[4]=m1.x; mr[5]=m1.y; mr[6]=m1.z; mr[7]=m1.w;
        mr[8]=m2.x; mr[9]=m2.y; mr[10]=m2.z; mr[11]=m2.w;
        mr[12]=m3.x; mr[13]=m3.y; mr[14]=m3.z; mr[15]=m3.w;
    }
    float R = 0.f;
    #pragma unroll
    for (int k = 0; k < 16; ++k) R += mr[k];

    // ---- qd dots (cur rows vs mr) ----
    float qd[4];
    #pragma unroll
    for (int j = 0; j < 4; ++j) {
        float acc0 = 0.f;
        #pragma unroll
        for (int k = 0; k < 16; ++k)
            acc0 = fmaf(qget(cq[j][k >> 2], k & 3), mr[k], acc0);
        qd[j] = acc0;
    }

    // ---- pd dots: prev rows 0-1 (in flight), then load+dot rows 2-3 ----
    float pd = 0.f, pdiag = 0.f;
    #pragma unroll
    for (int j = 0; j < 2; ++j) {
        #pragma unroll
        for (int k = 0; k < 16; ++k)
            pd = fmaf(qget(pq[j][k >> 2], k & 3), mr[k], pd);
        pdiag += qget(pq[j][j], kb);
    }
    #pragma unroll
    for (int j = 2; j < 4; ++j) {
        const float4* src = (const float4*)(Gp + rbase + (j << 10));
        float4 q0 = src[0], q1 = src[1], q2 = src[2], q3 = src[3];
        float4 rr[4] = {q0, q1, q2, q3};
        #pragma unroll
        for (int k = 0; k < 16; ++k)
            pd = fmaf(qget(rr[k >> 2], k & 3), mr[k], pd);
        pdiag += qget(rr[j], kb);
    }

    // ---- T reductions: lanes {iu, iu+16, iu+32, iu+48} cover planes 0..15 ----
    tc    += __shfl_xor(tc, 16);    tc    += __shfl_xor(tc, 32);    // Tcur[iu]
    pdiag += __shfl_xor(pdiag, 16); pdiag += __shfl_xor(pdiag, 32); // Tprev[iu]
    const float dT = pdiag - tc;

    // ---- MFMA: all 8 K-steps in this wave (lane role: col=iu, hi=kb) ----
    f32x4 acc = {0.f, 0.f, 0.f, 0.f};
    #pragma unroll
    for (int S = 0; S < 8; ++S) {
        bf16x8 av = *(const bf16x8*)&XA[iu][(S << 5) + (kb << 3)];
        const int brow = 2 * S + (kb >> 1);
        const int cb = ((kb & 1) << 7) + iu;
        bf16x8 bv;
        #pragma unroll
        for (int e = 0; e < 8; ++e)
            bv[e] = (short)XA[brow][cb + (e << 4)];
        acc = __builtin_amdgcn_mfma_f32_16x16x32_bf16(av, bv, acc, 0, 0, 0);
    }
    // term4 contraction: D rows 4*kb+q, col iu
    float t4c = acc[0] * MINV[(kb << 2) + 0][iu]
              + acc[1] * MINV[(kb << 2) + 1][iu]
              + acc[2] * MINV[(kb << 2) + 2][iu]
              + acc[3] * MINV[(kb << 2) + 3][iu];

    // ---- combine: s = pd + sum_j (T[k_j]-1)*qd[j] - 0.25*dT*R - t4c ----
    float s = pd - 0.25f * dT * R - t4c;
    #pragma unroll
    for (int j = 0; j < 4; ++j) {
        float Tk = __shfl(tc, kb + 4 * j);   // lane x holds Tcur[x&15]
        s = fmaf(Tk - 1.0f, qd[j], s);
    }

    // ---- wave sum, lane 0 writes ----
    #pragma unroll
    for (int w2 = 1; w2 < 64; w2 <<= 1)
        s += __shfl_xor(s, w2);
    if (l == 0) out[b] = s;
}

extern "C" void kernel_launch(void* const* d_in, const int* in_sizes, int n_in,
                              void* d_out, int out_size, void* d_ws, size_t ws_size,
                              hipStream_t stream) {
    const float* metric = (const float*)d_in[0];   // (2048, 16, 16) f32
    const float* gamma  = (const float*)d_in[1];   // (2048, 16, 16, 16) f32
    float* out = (float*)d_out;                    // (2048,) f32
    curvature_kernel<<<NB, 64, 0, stream>>>(metric, gamma, out);
}

// Round 11
// 13.088 us; speedup vs baseline: 1.9685x; 1.9685x over previous
//
#include <hip/hip_runtime.h>
#include <hip/hip_bf16.h>

#define NB 2048

typedef __attribute__((ext_vector_type(8))) short bf16x8;
typedef __attribute__((ext_vector_type(4))) float f32x4;

__device__ __forceinline__ float qget(const float4& q, int c) {
    return c == 0 ? q.x : c == 1 ? q.y : c == 2 ? q.z : q.w;
}

// One block per batch (2048 blocks, 256 thr). Thread t owns cur row (ku,iu)=G[b,ku,iu,:].
// scalar[b] = <Aprev-Acur,Minv> - sum_i dT[i]*R[i] + sum_m T[m]*Q[m] - <term4,Minv>
// term4 = 16x16x256 bf16 MFMA: A[i][l]=G[m,i,k], B[l][j]=G[k,m,j], l=m*16+k.
//   XA[b][a*16+c]=G[a,b,c] serves both fragments (B via u16 gather, slot-consistent l).
// Register diet for occupancy 6 (24 waves/CU): prev tile is NOT held in regs —
// streamed post-barA with immediate fma consumption (same-XCD L2 hits).
__global__ __launch_bounds__(256, 6)
void curvature_kernel(const float* __restrict__ metric,
                      const float* __restrict__ gamma,
                      float* __restrict__ out)
{
    const int bid = blockIdx.x;
    const int b = ((bid & 7) << 8) | (bid >> 3);   // XCD swizzle: b, b-1 share an L2
    const int t = threadIdx.x;
    const int wv = t >> 6, lane = t & 63;
    const int ku = t >> 4, iu = t & 15;
    const int r16 = lane & 15, hi = lane >> 4;
    const int gjw = b & 3;                          // GJ wave id: spread across SIMDs

    __shared__ alignas(16) unsigned short XA[16][264];  // XA[b][a*16+c] = G[a,b,c]
    __shared__ alignas(16) float MINV[16][20];
    __shared__ alignas(16) float TT[16][20];             // TT[m][k] = G[k,m,k]
    __shared__ float red[4];

    const float* Gc = gamma + ((size_t)b << 12);
    const float* Gp = gamma + ((size_t)((b + NB - 1) & (NB - 1)) << 12);

    // ---- cur-tile loads (16 regs) + metric (GJ wave only) ----
    const float4* gc4 = (const float4*)(Gc + (t << 4));
    float4 g0 = gc4[0], g1 = gc4[1], g2 = gc4[2], g3 = gc4[3];
    float4 mrow = {0.f, 0.f, 0.f, 0.f};
    const bool isGJ = (wv == gjw);
    if (isGJ) mrow = ((const float4*)(metric + ((size_t)b << 8)))[lane];

    // ---- GJ wave: shuffle-only Gauss-Jordan inverse, BEFORE barA ----
    if (isGJ) {
        const int gi = lane >> 2, gq2 = lane & 3;
        float a0 = mrow.x, a1 = mrow.y, a2 = mrow.z, a3 = mrow.w;
        #pragma unroll
        for (int k = 0; k < 16; ++k) {
            const int kq = k >> 2, kc = k & 3;
            float akc = (kc == 0) ? a0 : (kc == 1) ? a1 : (kc == 2) ? a2 : a3;
            float pv = __shfl(akc, (k << 2) | kq);
            float f  = __shfl(akc, (lane & 60) | kq);
            float q0 = __shfl(a0, (k << 2) | gq2);
            float q1 = __shfl(a1, (k << 2) | gq2);
            float q2 = __shfl(a2, (k << 2) | gq2);
            float q3 = __shfl(a3, (k << 2) | gq2);
            float pinv = 1.0f / pv;
            bool piv = (gi == k);
            float r0 = q0*pinv, r1 = q1*pinv, r2 = q2*pinv, r3 = q3*pinv;
            a0 = piv ? r0 : fmaf(-f, r0, a0);
            a1 = piv ? r1 : fmaf(-f, r1, a1);
            a2 = piv ? r2 : fmaf(-f, r2, a2);
            a3 = piv ? r3 : fmaf(-f, r3, a3);
            if (gq2 == kq) {
                float colv = piv ? pinv : -f * pinv;
                if      (kc == 0) a0 = colv;
                else if (kc == 1) a1 = colv;
                else if (kc == 2) a2 = colv;
                else              a3 = colv;
            }
        }
        MINV[gi][4*gq2 + 0] = a0;
        MINV[gi][4*gq2 + 1] = a1;
        MINV[gi][4*gq2 + 2] = a2;
        MINV[gi][4*gq2 + 3] = a3;
    }

    // ---- pack cur row to bf16, stage XA (contiguous b128) + diag to TT ----
    float gku;
    {
        float4 gq[4] = {g0, g1, g2, g3};
        unsigned yp[8];
        #pragma unroll
        for (int q = 0; q < 8; ++q) {
            union { __hip_bfloat162 h; unsigned u; } cv;
            cv.h = __float22bfloat162_rn(
                make_float2(qget(gq[q >> 1], (q & 1) * 2),
                            qget(gq[q >> 1], (q & 1) * 2 + 1)));
            yp[q] = cv.u;
        }
        uint4* xd = (uint4*)&XA[iu][ku << 4];
        xd[0] = make_uint4(yp[0], yp[1], yp[2], yp[3]);
        xd[1] = make_uint4(yp[4], yp[5], yp[6], yp[7]);
        gku = g0.x;                     // cur[ku,iu,ku] via cndmask chain
        #pragma unroll
        for (int k = 1; k < 16; ++k) {
            float v = qget(gq[k >> 2], k & 3);
            gku = (ku == k) ? v : gku;
        }
    }
    TT[iu][ku] = gku;
    __syncthreads();   // barA: XA, TT, MINV visible

    // ---- mr = MINV[iu][:] ----
    float mr[16];
    {
        const float4* mv = (const float4*)&MINV[iu][0];
        float4 m0 = mv[0], m1 = mv[1], m2 = mv[2], m3 = mv[3];
        mr[0]=m0.x; mr[1]=m0.y; mr[2]=m0.z; mr[3]=m0.w;
        mr[4]=m1.x; mr[5]=m1.y; mr[6]=m1.z; mr[7]=m1.w;
        mr[8]=m2.x; mr[9]=m2.y; mr[10]=m2.z; mr[11]=m2.w;
        mr[12]=m3.x; mr[13]=m3.y; mr[14]=m3.z; mr[15]=m3.w;
    }

    // ---- every wave: 2 K-steps of the 16x16x256 MFMA ----
    f32x4 acc = {0.f, 0.f, 0.f, 0.f};
    #pragma unroll
    for (int s = 0; s < 2; ++s) {
        const int S = 2 * wv + s;
        bf16x8 av = *(const bf16x8*)&XA[r16][(S << 5) + (hi << 3)];
        const int brow = 2 * S + (hi >> 1);
        const int cbase = ((hi & 1) << 7) + r16;
        bf16x8 bv;
        #pragma unroll
        for (int e = 0; e < 8; ++e)
            bv[e] = (short)XA[brow][cbase + (e << 4)];
        acc = __builtin_amdgcn_mfma_f32_16x16x32_bf16(av, bv, acc, 0, 0, 0);
    }

    // ---- stream prev row: pd = <prev,mr>, pku = prev[ku,iu,ku] (L2 hits) ----
    float pd = 0.f, pku = 0.f;
    {
        const float4* gp4 = (const float4*)(Gp + (t << 4));
        float4 v0 = gp4[0], v1 = gp4[1], v2 = gp4[2], v3 = gp4[3];
        float4 vq[4] = {v0, v1, v2, v3};
        #pragma unroll
        for (int k = 0; k < 16; ++k) {
            float v = qget(vq[k >> 2], k & 3);
            pd = fmaf(v, mr[k], pd);
            pku = (ku == k) ? v : pku;
        }
    }

    // ---- qd = <cur,mr>, R = sum mr ----
    float qd = 0.f, R = 0.f;
    {
        float4 gq[4] = {g0, g1, g2, g3};
        #pragma unroll
        for (int k = 0; k < 16; ++k) {
            float m = mr[k];
            qd = fmaf(qget(gq[k >> 2], k & 3), m, qd);
            R += m;
        }
    }

    // tcv = T[ku]: same-ku 16-lane group reduction
    float tcv = TT[ku][iu];
    #pragma unroll
    for (int w2 = 1; w2 < 16; w2 <<= 1)
        tcv += __shfl_xor(tcv, w2);

    float dt = pku - gku;
    // term4 contraction: D row = 4*hi+q, col = r16
    float t4c = acc[0] * MINV[(hi << 2) + 0][r16]
              + acc[1] * MINV[(hi << 2) + 1][r16]
              + acc[2] * MINV[(hi << 2) + 2][r16]
              + acc[3] * MINV[(hi << 2) + 3][r16];
    float s = fmaf(tcv - 1.0f, qd, pd) - dt * R - t4c;  // (pd-qd)+tcv*qd-dt*R-t4c

    #pragma unroll
    for (int w2 = 1; w2 < 64; w2 <<= 1)
        s += __shfl_xor(s, w2);
    if (lane == 0) red[wv] = s;
    __syncthreads();
    if (t == 0) out[b] = (red[0] + red[1]) + (red[2] + red[3]);
}

extern "C" void kernel_launch(void* const* d_in, const int* in_sizes, int n_in,
                              void* d_out, int out_size, void* d_ws, size_t ws_size,
                              hipStream_t stream) {
    const float* metric = (const float*)d_in[0];   // (2048, 16, 16) f32
    const float* gamma  = (const float*)d_in[1];   // (2048, 16, 16, 16) f32
    float* out = (float*)d_out;                    // (2048,) f32
    curvature_kernel<<<NB, 256, 0, stream>>>(metric, gamma, out);
}